// Round 8
// baseline (87.890 us; speedup 1.0000x reference)
//
#include <hip/hip_runtime.h>

#define B     512
#define NBG   10000
#define F     32
#define H     128
#define CHUNK 20
#define NBLK  500      // NBLK*CHUNK == NBG exactly
#define RB    8        // batch rows per MLP block
#define MLPBLK (B / RB)     // 64

// ws layout (floats): XT[F*B] | babsT[F*B] | accW[B] | accY[B] | cnt(1, as uint)

// ---------------- Kernel A: MLP -> XT[f][b], babsT[f][b]; block 0 zeroes accumulators ----------------
__global__ __launch_bounds__(128) void prep_kernel(
    const float* __restrict__ X,
    const float* __restrict__ W0, const float* __restrict__ b0,
    const float* __restrict__ W1, const float* __restrict__ b1,
    const float* __restrict__ Wout, const float* __restrict__ bout,
    float* __restrict__ XT,
    float* __restrict__ babsT,
    float* __restrict__ acc_zero)   // accW|accY|cnt : 2*B+1 words
{
    __shared__ __align__(16) float xr[RB * F];
    __shared__ __align__(16) float h0[RB * H];
    __shared__ __align__(16) float h1[RB * H];
    const int t  = threadIdx.x;
    const int r0 = blockIdx.x * RB;

    if (blockIdx.x == 0) {
        for (int i = t; i < 2 * B + 1; i += 128) acc_zero[i] = 0.f;  // 0u bits
    }

    for (int i = t; i < RB * F; i += 128) {
        int r = i >> 5, f = i & 31;
        float xv = X[(r0 + r) * F + f];
        xr[r * F + f] = xv;
        XT[f * B + r0 + r] = xv;
    }
    __syncthreads();

    float acc[RB];
    #pragma unroll
    for (int r = 0; r < RB; ++r) acc[r] = b0[t];
    #pragma unroll
    for (int f4 = 0; f4 < F / 4; ++f4) {
        float wa = W0[(4*f4+0)*H + t];
        float wb = W0[(4*f4+1)*H + t];
        float wc = W0[(4*f4+2)*H + t];
        float wd = W0[(4*f4+3)*H + t];
        #pragma unroll
        for (int r = 0; r < RB; ++r) {
            float4 xv = *(const float4*)&xr[r * F + 4*f4];
            acc[r] += xv.x*wa + xv.y*wb + xv.z*wc + xv.w*wd;
        }
    }
    #pragma unroll
    for (int r = 0; r < RB; ++r) h0[r * H + t] = fmaxf(acc[r], 0.f);
    __syncthreads();

    #pragma unroll
    for (int r = 0; r < RB; ++r) acc[r] = b1[t];
    #pragma unroll 8
    for (int j4 = 0; j4 < H / 4; ++j4) {
        float wa = W1[(4*j4+0)*H + t];
        float wb = W1[(4*j4+1)*H + t];
        float wc = W1[(4*j4+2)*H + t];
        float wd = W1[(4*j4+3)*H + t];
        #pragma unroll
        for (int r = 0; r < RB; ++r) {
            float4 hv = *(const float4*)&h0[r * H + 4*j4];
            acc[r] += hv.x*wa + hv.y*wb + hv.z*wc + hv.w*wd;
        }
    }
    #pragma unroll
    for (int r = 0; r < RB; ++r) h1[r * H + t] = fmaxf(acc[r], 0.f);
    __syncthreads();

    for (int i = t; i < RB * F; i += 128) {
        int r = i >> 5, f = i & 31;
        float a = bout[f];
        #pragma unroll 8
        for (int j4 = 0; j4 < H / 4; ++j4) {
            float4 hv = *(const float4*)&h1[r * H + 4*j4];
            a += hv.x*Wout[(4*j4+0)*F + f] + hv.y*Wout[(4*j4+1)*F + f]
               + hv.z*Wout[(4*j4+2)*F + f] + hv.w*Wout[(4*j4+3)*F + f];
        }
        babsT[f * B + r0 + r] = fabsf(a);
    }
}

// ---------------- Kernel B: NW sums + fused final reduction ----------------
// Thread = batch row b. Block = chunk of CHUNK=20 points (LDS-broadcast).
// Partials go to device-scope fp32 atomics (500 adds/address, overlapped);
// last block (completion counter) computes out[b] = accY/accW, reading the
// accumulators via atomicAdd(p, 0.0f) so reads hit the coherence point
// (no cross-XCD stale-L2 hazard).
__global__ __launch_bounds__(512, 4) void nw_fused(
    const float* __restrict__ XT,
    const float* __restrict__ babsT,
    const float* __restrict__ xbg,
    const float* __restrict__ ybg,
    float* __restrict__ accW,
    float* __restrict__ accY,
    unsigned* __restrict__ cnt,
    float* __restrict__ out)
{
    __shared__ __align__(16) float tile[CHUNK * F];   // 2560 B
    __shared__ float ytile[CHUNK];
    __shared__ unsigned last;

    const int b  = threadIdx.x;
    const int n0 = blockIdx.x * CHUNK;

    // stage chunk: 640 contiguous floats + 20 y values (coalesced)
    tile[b] = xbg[n0 * F + b];
    if (b < CHUNK * F - 512) tile[512 + b] = xbg[n0 * F + 512 + b];
    if (b < CHUNK) ytile[b] = ybg[n0 + b];

    // preload row data (independent of LDS, overlaps staging)
    float xq[F], bv[F];
    #pragma unroll
    for (int f = 0; f < F; ++f) {
        xq[f] = XT[f * B + b];          // coalesced 256B/wave
        bv[f] = babsT[f * B + b];
    }
    __syncthreads();

    const float4* t4 = (const float4*)tile;
    float sw = 0.f, swy = 0.f;

    #pragma unroll 5
    for (int j = 0; j < CHUNK; ++j) {
        float da = 0.f, db = 0.f;
        #pragma unroll
        for (int q = 0; q < F / 4; ++q) {
            float4 v = t4[j * (F / 4) + q];   // lane-uniform addr -> broadcast
            da += bv[4*q+0] * fabsf(xq[4*q+0] - v.x);
            db += bv[4*q+1] * fabsf(xq[4*q+1] - v.y);
            da += bv[4*q+2] * fabsf(xq[4*q+2] - v.z);
            db += bv[4*q+3] * fabsf(xq[4*q+3] - v.w);
        }
        float w = __expf(-(da + db));
        sw  += w;
        swy += w * ytile[j];
    }

    atomicAdd(&accW[b], sw);
    atomicAdd(&accY[b], swy);
    __threadfence();                    // drain our atomics (vmcnt) + device fence
    __syncthreads();
    if (b == 0) last = atomicAdd(cnt, 1u);
    __syncthreads();

    if (last == NBLK - 1) {
        // all 500 blocks' adds are complete; read via atomics (coherent)
        float w = atomicAdd(&accW[b], 0.0f);
        float y = atomicAdd(&accY[b], 0.0f);
        out[b] = y / w;
    }
}

extern "C" void kernel_launch(void* const* d_in, const int* in_sizes, int n_in,
                              void* d_out, int out_size, void* d_ws, size_t ws_size,
                              hipStream_t stream)
{
    const float* X    = (const float*)d_in[0];
    const float* xbg  = (const float*)d_in[1];
    const float* ybg  = (const float*)d_in[2];
    const float* W0   = (const float*)d_in[3];
    const float* b0   = (const float*)d_in[4];
    const float* W1   = (const float*)d_in[5];
    const float* b1   = (const float*)d_in[6];
    const float* Wout = (const float*)d_in[7];
    const float* bout = (const float*)d_in[8];
    float* out = (float*)d_out;

    float*    XT    = (float*)d_ws;           // F*B
    float*    babsT = XT + F * B;             // F*B
    float*    accW  = babsT + F * B;          // B
    float*    accY  = accW + B;               // B
    unsigned* cnt   = (unsigned*)(accY + B);  // 1

    prep_kernel<<<MLPBLK, 128, 0, stream>>>(X, W0, b0, W1, b1, Wout, bout,
                                            XT, babsT, accW);
    nw_fused<<<NBLK, B, 0, stream>>>(XT, babsT, xbg, ybg, accW, accY, cnt, out);
}